// Round 1
// baseline (1078.865 us; speedup 1.0000x reference)
//
#include <hip/hip_runtime.h>

// MultiHeadedAttention (temporal mask) for MI355X / gfx950.
// Strategy: everything on bf16 MFMA with hi/lo split (3-term) => ~fp32 accuracy,
// two-pass softmax (no max needed: scores ~ N(0,1)), p_attn streamed once.

typedef __attribute__((ext_vector_type(8))) short bf16x8;
typedef __attribute__((ext_vector_type(4))) float f32x4;

#define MFMA16(a,b,c) __builtin_amdgcn_mfma_f32_16x16x32_bf16((a),(b),(c),0,0,0)

static __device__ __forceinline__ unsigned short f2bf(float f){
  unsigned int u = __float_as_uint(f);
  u += 0x7fffu + ((u >> 16) & 1u);
  return (unsigned short)(u >> 16);
}
static __device__ __forceinline__ float bf2f(unsigned short h){
  return __uint_as_float(((unsigned int)h) << 16);
}

// ---------------- convert x -> hi/lo bf16 ----------------
__global__ __launch_bounds__(256) void cvt_x(const float* __restrict__ x,
    unsigned short* __restrict__ xh, unsigned short* __restrict__ xl)
{
  size_t i = ((size_t)blockIdx.x * 256 + threadIdx.x) * 8;   // grid sized exactly
  float4 a = *(const float4*)(x + i);
  float4 b = *(const float4*)(x + i + 4);
  float v[8] = {a.x,a.y,a.z,a.w,b.x,b.y,b.z,b.w};
  unsigned int hp[4], lp[4];
#pragma unroll
  for(int j=0;j<4;j++){
    unsigned short h0 = f2bf(v[2*j]);
    unsigned short h1 = f2bf(v[2*j+1]);
    unsigned short l0 = f2bf(v[2*j]   - bf2f(h0));
    unsigned short l1 = f2bf(v[2*j+1] - bf2f(h1));
    hp[j] = (unsigned)h0 | ((unsigned)h1 << 16);
    lp[j] = (unsigned)l0 | ((unsigned)l1 << 16);
  }
  *(uint4*)(xh + i) = make_uint4(hp[0],hp[1],hp[2],hp[3]);
  *(uint4*)(xl + i) = make_uint4(lp[0],lp[1],lp[2],lp[3]);
}

// ---- weights -> TRANSPOSED hi/lo bf16: wt[mat][n(512)][k(256)] ----
__global__ __launch_bounds__(256) void cvt_w(const float* __restrict__ wq,
    const float* __restrict__ wk, const float* __restrict__ wv,
    unsigned short* __restrict__ wth, unsigned short* __restrict__ wtl)
{
  int idx = blockIdx.x * 256 + threadIdx.x;      // < 3*131072
  int mat = idx >> 17;
  int rem = idx & 131071;
  int kk  = rem >> 9;       // row in w [256][512]
  int nn  = rem & 511;      // col
  const float* w = (mat == 0) ? wq : ((mat == 1) ? wk : wv);
  float v = w[rem];
  unsigned short h = f2bf(v);
  unsigned short l = f2bf(v - bf2f(h));
  int o = mat * 131072 + nn * 256 + kk;
  wth[o] = h; wtl[o] = l;
}

// stage a 64x64 bf16 tile (row stride = rstride elems) into padded LDS [64][72]
static __device__ __forceinline__ void stage64(unsigned short (*dst)[72],
    const unsigned short* __restrict__ src, int rstride, int tid)
{
  int r = tid >> 2, c = (tid & 3) << 4;
  const uint4* s = (const uint4*)(src + (size_t)r * rstride + c);
  uint4 a = s[0]; uint4 b = s[1];
  *(uint4*)&dst[r][c]     = a;
  *(uint4*)&dst[r][c + 8] = b;
}

// ---------------- fused QKV projection ----------------
// x[12800,256] @ w[256,512] (+bias, relu on v), 3-term hi/lo split MFMA.
// Outputs: q,k as [bh][s][64] hi/lo ; v TRANSPOSED as [bh][64 d][1600 s] hi/lo.
__global__ __launch_bounds__(256,2) void proj(
    const unsigned short* __restrict__ xh, const unsigned short* __restrict__ xl,
    const unsigned short* __restrict__ wth, const unsigned short* __restrict__ wtl,
    const float* __restrict__ bq, const float* __restrict__ bk, const float* __restrict__ bv,
    unsigned short* __restrict__ qh, unsigned short* __restrict__ ql,
    unsigned short* __restrict__ kh, unsigned short* __restrict__ kl,
    unsigned short* __restrict__ vth, unsigned short* __restrict__ vtl)
{
  __shared__ unsigned short wsh[3][64][72], wsl[3][64][72];   // 55,296 B
  const int tid = threadIdx.x, lane = tid & 63, w = tid >> 6;
  const int g = lane >> 4, lam = lane & 15;
  const int nt = blockIdx.x;            // head / n-tile (64 cols)
  const int mt = blockIdx.y;            // m-tile (64 rows)
  const int m0 = mt * 64, n0 = nt * 64;
  const int wr = w >> 1, wc = w & 1;

  f32x4 acc[3][2][2];
#pragma unroll
  for(int m=0;m<3;m++)
#pragma unroll
    for(int i=0;i<2;i++)
#pragma unroll
      for(int j=0;j<2;j++) acc[m][i][j] = f32x4{0.f,0.f,0.f,0.f};

  for(int k0 = 0; k0 < 256; k0 += 64){
    __syncthreads();
#pragma unroll
    for(int m=0;m<3;m++){
      stage64(wsh[m], wth + m*131072 + n0*256 + k0, 256, tid);
      stage64(wsl[m], wtl + m*131072 + n0*256 + k0, 256, tid);
    }
    __syncthreads();
#pragma unroll
    for(int ks=0;ks<2;ks++){
      bf16x8 ah[2], al[2];
#pragma unroll
      for(int mr=0;mr<2;mr++){
        size_t ro = (size_t)(m0 + wr*32 + mr*16 + lam) * 256 + k0 + ks*32 + g*8;
        ah[mr] = *(const bf16x8*)(xh + ro);
        al[mr] = *(const bf16x8*)(xl + ro);
      }
#pragma unroll
      for(int m=0;m<3;m++){
#pragma unroll
        for(int nc=0;nc<2;nc++){
          bf16x8 bh8 = *(const bf16x8*)&wsh[m][wc*32 + nc*16 + lam][ks*32 + g*8];
          bf16x8 bl8 = *(const bf16x8*)&wsl[m][wc*32 + nc*16 + lam][ks*32 + g*8];
#pragma unroll
          for(int mr=0;mr<2;mr++){
            acc[m][mr][nc] = MFMA16(ah[mr], bh8, acc[m][mr][nc]);
            acc[m][mr][nc] = MFMA16(ah[mr], bl8, acc[m][mr][nc]);
            acc[m][mr][nc] = MFMA16(al[mr], bh8, acc[m][mr][nc]);
          }
        }
      }
    }
  }

  const int bb = m0 / 1600;
  const int s0 = m0 - bb * 1600;
#pragma unroll
  for(int m=0;m<3;m++){
    const float* bias = (m==0) ? bq : ((m==1) ? bk : bv);
#pragma unroll
    for(int mr=0;mr<2;mr++){
#pragma unroll
      for(int nc=0;nc<2;nc++){
        int d = wc*32 + nc*16 + lam;
        float bsv = bias[n0 + d];
#pragma unroll
        for(int r=0;r<4;r++){
          int s = s0 + wr*32 + mr*16 + g*4 + r;
          float v = acc[m][mr][nc][r] + bsv;
          if(m==2) v = fmaxf(v, 0.f);
          unsigned short hi = f2bf(v);
          unsigned short lo = f2bf(v - bf2f(hi));
          if(m==0){
            size_t o = (((size_t)bb*8 + nt)*1600 + s)*64 + d;
            qh[o]=hi; ql[o]=lo;
          } else if(m==1){
            size_t o = (((size_t)bb*8 + nt)*1600 + s)*64 + d;
            kh[o]=hi; kl[o]=lo;
          } else {
            size_t o = (((size_t)bb*8 + nt)*64 + d)*1600 + s;   // transposed
            vth[o]=hi; vtl[o]=lo;
          }
        }
      }
    }
  }
}

// ---------------- fused attention ----------------
// One block: 64 q-rows of one (b,h). 4 waves x 16 q-rows each.
// Pass 1: row sums of exp(s) (no max needed). Pass 2: recompute scores,
// write p_attn, accumulate O = P V via LDS round-trip of P (hi/lo).
__global__ __launch_bounds__(256,2) void attn(
    const unsigned short* __restrict__ qh, const unsigned short* __restrict__ ql,
    const unsigned short* __restrict__ kh, const unsigned short* __restrict__ kl,
    const unsigned short* __restrict__ vth, const unsigned short* __restrict__ vtl,
    float* __restrict__ out, float* __restrict__ pattn)
{
  __shared__ unsigned short Kh[64][72], Kl[64][72];
  __shared__ unsigned short Vh[64][72], Vl[64][72];
  __shared__ unsigned short Ph[64][72], Pl[64][72];     // total 55,296 B
  const int tid = threadIdx.x, lane = tid & 63, w = tid >> 6;
  const int g = lane >> 4, lam = lane & 15;
  const int qt = blockIdx.x, bh = blockIdx.y;
  const int q0 = qt * 64;
  const float SC = 0.18033688011112042f;   // 0.125 * log2(e)

  // Q fragments straight from global (no LDS needed)
  bf16x8 qfh[2], qfl[2];
#pragma unroll
  for(int ks=0;ks<2;ks++){
    size_t ro = ((size_t)bh*1600 + q0 + w*16 + lam)*64 + ks*32 + g*8;
    qfh[ks] = *(const bf16x8*)(qh + ro);
    qfl[ks] = *(const bf16x8*)(ql + ro);
  }
  int qrow[4], fq[4];
#pragma unroll
  for(int r=0;r<4;r++){ qrow[r] = q0 + w*16 + g*4 + r; fq[r] = qrow[r]/25; }

  const unsigned short* khg = kh  + (size_t)bh*1600*64;
  const unsigned short* klg = kl  + (size_t)bh*1600*64;
  const unsigned short* vhg = vth + (size_t)bh*64*1600;
  const unsigned short* vlg = vtl + (size_t)bh*64*1600;

  // ---------- pass 1: row sums ----------
  float sums[4] = {0.f,0.f,0.f,0.f};
  for(int kt=0; kt<25; kt++){
    __syncthreads();
    stage64(Kh, khg + kt*64*64, 64, tid);
    stage64(Kl, klg + kt*64*64, 64, tid);
    __syncthreads();
    f32x4 sc4[4];
#pragma unroll
    for(int t=0;t<4;t++) sc4[t] = f32x4{0.f,0.f,0.f,0.f};
#pragma unroll
    for(int ks=0;ks<2;ks++){
#pragma unroll
      for(int t=0;t<4;t++){
        bf16x8 kbh = *(const bf16x8*)&Kh[t*16 + lam][ks*32 + g*8];
        bf16x8 kbl = *(const bf16x8*)&Kl[t*16 + lam][ks*32 + g*8];
        sc4[t] = MFMA16(qfh[ks], kbh, sc4[t]);
        sc4[t] = MFMA16(qfh[ks], kbl, sc4[t]);
        sc4[t] = MFMA16(qfl[ks], kbh, sc4[t]);
      }
    }
#pragma unroll
    for(int t=0;t<4;t++){
      int k = kt*64 + t*16 + lam;
      int fk = k / 25;
#pragma unroll
      for(int r=0;r<4;r++){
        bool msk = (fk == fq[r]) && (k != qrow[r]);
        float e = msk ? 0.f : exp2f(sc4[t][r] * SC);
        sums[r] += e;
      }
    }
  }
  float rl[4];
#pragma unroll
  for(int r=0;r<4;r++){
    float s = sums[r];
    s += __shfl_xor(s, 1, 64);
    s += __shfl_xor(s, 2, 64);
    s += __shfl_xor(s, 4, 64);
    s += __shfl_xor(s, 8, 64);
    rl[r] = 1.0f / s;
  }

  // ---------- pass 2: p_attn + O ----------
  f32x4 oacc[4];
#pragma unroll
  for(int td=0;td<4;td++) oacc[td] = f32x4{0.f,0.f,0.f,0.f};
  float* pat = pattn + (size_t)bh*1600*1600;

  for(int kt=0; kt<25; kt++){
    __syncthreads();
    stage64(Kh, khg + kt*64*64, 64, tid);
    stage64(Kl, klg + kt*64*64, 64, tid);
    stage64(Vh, vhg + kt*64, 1600, tid);
    stage64(Vl, vlg + kt*64, 1600, tid);
    __syncthreads();
    f32x4 sc4[4];
#pragma unroll
    for(int t=0;t<4;t++) sc4[t] = f32x4{0.f,0.f,0.f,0.f};
#pragma unroll
    for(int ks=0;ks<2;ks++){
#pragma unroll
      for(int t=0;t<4;t++){
        bf16x8 kbh = *(const bf16x8*)&Kh[t*16 + lam][ks*32 + g*8];
        bf16x8 kbl = *(const bf16x8*)&Kl[t*16 + lam][ks*32 + g*8];
        sc4[t] = MFMA16(qfh[ks], kbh, sc4[t]);
        sc4[t] = MFMA16(qfh[ks], kbl, sc4[t]);
        sc4[t] = MFMA16(qfl[ks], kbh, sc4[t]);
      }
    }
#pragma unroll
    for(int t=0;t<4;t++){
      int k = kt*64 + t*16 + lam;
      int fk = k / 25;
#pragma unroll
      for(int r=0;r<4;r++){
        bool msk = (fk == fq[r]) && (k != qrow[r]);
        float p = msk ? 0.f : exp2f(sc4[t][r] * SC) * rl[r];
        pat[(size_t)qrow[r]*1600 + k] = p;
        unsigned short hi = f2bf(p);
        unsigned short lo = f2bf(p - bf2f(hi));
        Ph[w*16 + g*4 + r][t*16 + lam] = hi;
        Pl[w*16 + g*4 + r][t*16 + lam] = lo;
      }
    }
    // PV (wave-private P rows: no barrier needed, in-wave LDS order suffices)
#pragma unroll
    for(int ks=0;ks<2;ks++){
      bf16x8 pah = *(const bf16x8*)&Ph[w*16 + lam][ks*32 + g*8];
      bf16x8 pal = *(const bf16x8*)&Pl[w*16 + lam][ks*32 + g*8];
#pragma unroll
      for(int td=0;td<4;td++){
        bf16x8 vbh = *(const bf16x8*)&Vh[td*16 + lam][ks*32 + g*8];
        bf16x8 vbl = *(const bf16x8*)&Vl[td*16 + lam][ks*32 + g*8];
        oacc[td] = MFMA16(pah, vbh, oacc[td]);
        oacc[td] = MFMA16(pah, vbl, oacc[td]);
        oacc[td] = MFMA16(pal, vbh, oacc[td]);
      }
    }
  }

  const int bb = bh >> 3, hh = bh & 7;
#pragma unroll
  for(int td=0;td<4;td++){
#pragma unroll
    for(int r=0;r<4;r++){
      out[((size_t)bb*1600 + qrow[r])*512 + hh*64 + td*16 + lam] = oacc[td][r];
    }
  }
}

extern "C" void kernel_launch(void* const* d_in, const int* in_sizes, int n_in,
                              void* d_out, int out_size, void* d_ws, size_t ws_size,
                              hipStream_t stream)
{
  const float* x  = (const float*)d_in[0];
  const float* wq = (const float*)d_in[1];
  const float* bq = (const float*)d_in[2];
  const float* wk = (const float*)d_in[3];
  const float* bk = (const float*)d_in[4];
  const float* wv = (const float*)d_in[5];
  const float* bv = (const float*)d_in[6];

  float* out   = (float*)d_out;
  float* pattn = out + (size_t)8*1600*512;     // 6,553,600 floats of `out` first

  // workspace layout (ushort elems), total ~93.3 MB
  unsigned short* ws  = (unsigned short*)d_ws;
  unsigned short* xh  = ws;
  unsigned short* xl  = xh  + 3276800;
  unsigned short* wth = xl  + 3276800;
  unsigned short* wtl = wth + 393216;
  unsigned short* qh  = wtl + 393216;
  unsigned short* ql  = qh  + 6553600;
  unsigned short* kh  = ql  + 6553600;
  unsigned short* kl  = kh  + 6553600;
  unsigned short* vth = kl  + 6553600;
  unsigned short* vtl = vth + 6553600;

  cvt_x<<<1600, 256, 0, stream>>>(x, xh, xl);
  cvt_w<<<1536, 256, 0, stream>>>(wq, wk, wv, wth, wtl);
  proj<<<dim3(8, 200), 256, 0, stream>>>(xh, xl, wth, wtl, bq, bk, bv,
                                         qh, ql, kh, kl, vth, vtl);
  attn<<<dim3(25, 64), 256, 0, stream>>>(qh, ql, kh, kl, vth, vtl, out, pattn);
}